// Round 8
// baseline (1192.650 us; speedup 1.0000x reference)
//
#include <hip/hip_runtime.h>
#include <hip/hip_fp16.h>

// N=1024, F=22, T=1000, H=64, gates 4H=256
// R8: BARRIER-FREE dataflow. 16 waves, one unit per wave:
//   waves 0-3: L2 ; 4-7: L1 ; 8-11: L0 ; 12-13: x stager ; 14-15 idle.
// Ring-depth-4 LDS tick buffers; per-wave progress flags (monotone tick
// counters) in LDS; consumers spin on min4(flags) with backpressure:
//   L0(t):  p3>=t,   p0>=t-1, p1>=t-4
//   L1(t):  p0>=t,   p1>=t-1, p2>=t-4
//   L2(t):  p1>=t,   p2>=t-1
//   stg(t): p0>=t-4
// Slot s of a ring holds {input(t), h_rec(t-1)} for t = s mod 4.
// A-rows replicated via addressing (row=l15&3) -> C reg r = batch r; z via 3 cndmask.
#define TT 1000
#define FF 22
#define HH 64
#define BB 4       // batch per block
#define NBLK 256   // 1024/4 -> one block per CU
#define S0 112     // row stride (f16) layer0 [x(0:22)|pad|h0(32:96)|pad], 3 K-tiles
#define S1 144     // row stride (f16) layers1/2 [h_in(0:64)|h_rec(64:128)|pad], 4 K-tiles
#define SL0 (4 * S0)   // slot stride in0
#define SL1 (4 * S1)   // slot stride in1/in2

typedef _Float16 half8 __attribute__((ext_vector_type(8)));
typedef float float4v __attribute__((ext_vector_type(4)));

__device__ __forceinline__ float sigm(float v) { return 1.0f / (1.0f + __expf(-v)); }
__device__ __forceinline__ float tanh_(float v) { return 1.0f - 2.0f / (__expf(2.0f * v) + 1.0f); }

__device__ __forceinline__ float sel4(const float4v a, int q) {
    float lo = (q & 2) ? a[2] : a[0];
    float hi = (q & 2) ? a[3] : a[1];
    return (q & 1) ? hi : lo;
}

__device__ __forceinline__ float gate_update(const float z[4], float& c) {
    float cc = sigm(z[1]) * c + sigm(z[0]) * tanh_(z[2]);
    c = cc;
    return sigm(z[3]) * tanh_(cc);
}

__device__ __forceinline__ int min4i(const int* p) {
    int4 v = *(const int4*)p;
    return min(min(v.x, v.y), min(v.z, v.w));
}

__device__ __forceinline__ void poll1(const int* a, int ta) {
    for (;;) {
        asm volatile("" ::: "memory");
        if (min4i(a) >= ta) break;
        __builtin_amdgcn_s_sleep(1);
    }
    __threadfence_block();
}
__device__ __forceinline__ void poll2(const int* a, int ta, const int* b, int tb) {
    for (;;) {
        asm volatile("" ::: "memory");
        if (min4i(a) >= ta && min4i(b) >= tb) break;
        __builtin_amdgcn_s_sleep(1);
    }
    __threadfence_block();
}
__device__ __forceinline__ void poll3(const int* a, int ta, const int* b, int tb,
                                      const int* c, int tc) {
    for (;;) {
        asm volatile("" ::: "memory");
        if (min4i(a) >= ta && min4i(b) >= tb && min4i(c) >= tc) break;
        __builtin_amdgcn_s_sleep(1);
    }
    __threadfence_block();
}

extern "C" __global__ void __launch_bounds__(1024, 1)
lstm_fused(const float* __restrict__ x,
           const float* __restrict__ Wih0, const float* __restrict__ Whh0,
           const float* __restrict__ bih0, const float* __restrict__ bhh0,
           const float* __restrict__ Wih1, const float* __restrict__ Whh1,
           const float* __restrict__ bih1, const float* __restrict__ bhh1,
           const float* __restrict__ Wih2, const float* __restrict__ Whh2,
           const float* __restrict__ bih2, const float* __restrict__ bhh2,
           const float* __restrict__ w0, const float* __restrict__ b0,
           const float* __restrict__ w1, const float* __restrict__ b1,
           const float* __restrict__ w2, const float* __restrict__ b2,
           const float* __restrict__ w3, const float* __restrict__ b3,
           const float* __restrict__ g0, const float* __restrict__ be0,
           const float* __restrict__ m0, const float* __restrict__ v0,
           const float* __restrict__ g1, const float* __restrict__ be1,
           const float* __restrict__ m1, const float* __restrict__ v1,
           const float* __restrict__ g2, const float* __restrict__ be2,
           const float* __restrict__ m2, const float* __restrict__ v2,
           float* __restrict__ out)
{
    __shared__ __align__(16) _Float16 in0[4 * SL0];
    __shared__ __align__(16) _Float16 in1[4 * SL1];
    __shared__ __align__(16) _Float16 in2[4 * SL1];
    __shared__ __align__(16) int flags[16];  // [0..3]=L2, [4..7]=L1, [8..11]=L0, [12..15]=stager
    __shared__ float fcA[BB * 64];
    __shared__ float fcB[BB * 64];
    __shared__ float fcW[54 * 65];
    __shared__ float fcP[5 * 64];

    const int tid  = threadIdx.x;
    const int wv   = tid >> 6;      // 0..15
    const int role = wv >> 2;       // 0=L2, 1=L1, 2=L0, 3=stage
    const int w4   = wv & 3;        // colgroup within role
    const int l    = tid & 63;
    const int q    = l >> 4;
    const int l15  = l & 15;
    const int u    = 16 * w4 + l15; // hidden unit for this lane's update
    const int b    = q;             // batch row for this lane's update
    const int n0   = blockIdx.x * BB;

    for (int i = tid; i < 4 * SL0; i += 1024) in0[i] = (_Float16)0.0f;
    for (int i = tid; i < 4 * SL1; i += 1024) in1[i] = (_Float16)0.0f;
    for (int i = tid; i < 4 * SL1; i += 1024) in2[i] = (_Float16)0.0f;
    if (tid < 16) flags[tid] = (tid >= 14) ? (1 << 29) : -1; // waves 14/15 never signal

    // ---- weight B-fragments: ONE unit per wave ----
    half8 wf[4][4];
    float4v biasC[4];
    if (role == 2) {                 // layer 0
#pragma unroll
        for (int g = 0; g < 4; ++g) {
            const int row = 64 * g + u;
#pragma unroll
            for (int kt = 0; kt < 3; ++kt) {
                half8 h{};
#pragma unroll
                for (int j = 0; j < 8; ++j) {
                    const int k = 32 * kt + 8 * q + j;
                    float val = 0.0f;
                    if (k < 32) { if (k < FF) val = Wih0[row * FF + k]; }
                    else        { val = Whh0[row * HH + (k - 32)]; }
                    h[j] = (_Float16)val;
                }
                wf[g][kt] = h;
            }
            float bv = bih0[row] + bhh0[row];
            biasC[g] = float4v{bv, bv, bv, bv};
        }
    } else if (role < 2) {           // role 0 -> layer 2, role 1 -> layer 1
        const float* Wih = role ? Wih1 : Wih2;
        const float* Whh = role ? Whh1 : Whh2;
        const float* bih = role ? bih1 : bih2;
        const float* bhh = role ? bhh1 : bhh2;
#pragma unroll
        for (int g = 0; g < 4; ++g) {
            const int row = 64 * g + u;
#pragma unroll
            for (int kt = 0; kt < 4; ++kt) {
                half8 h{};
#pragma unroll
                for (int j = 0; j < 8; ++j) {
                    const int k = 32 * kt + 8 * q + j;
                    h[j] = (_Float16)((k < 64) ? Wih[row * HH + k] : Whh[row * HH + (k - 64)]);
                }
                wf[g][kt] = h;
            }
            float bv = bih[row] + bhh[row];
            biasC[g] = float4v{bv, bv, bv, bv};
        }
    }

    // ---- x staging lanes: waves 12-13, 88 items ----
    const int  st  = tid - 768;
    const bool xok = (role == 3) && (st >= 0) && (st < BB * FF);
    const int  xb  = xok ? (st / FF) : 0;
    const int  xf  = xok ? (st - xb * FF) : 0;
    const float* xp = x + ((size_t)(n0 + xb) * FF + xf) * TT;

    volatile int* vfl = (volatile int*)flags;

    __syncthreads();   // zero-init + flag-init visible to all

    const int arow = (role == 2) ? ((l15 & 3) * S0 + q * 8) : ((l15 & 3) * S1 + q * 8);
    float c = 0.f;

    if (role == 3) {
        if (wv < 14) {
            float xh = xok ? xp[0] : 0.f;
            for (int t = 0; t < TT; ++t) {
                poll1(flags + 8, t - 4);                       // L0 consumed slot's old x
                if (xok) in0[(t & 3) * SL0 + xb * S0 + xf] = (_Float16)xh;
                __threadfence_block();
                if (l == 0) vfl[12 + (wv - 12)] = t;
                if (xok) {                                      // issue AFTER flag: full-tick slack
                    const int tn = (t + 1 < TT) ? (t + 1) : (TT - 1);
                    xh = xp[tn];
                }
            }
        }
        // waves 14/15: nothing (flags pre-set huge)
    } else if (role == 2) {            // ===== L0 =====
        for (int t = 0; t < TT; ++t) {
            poll3(flags + 12, t, flags + 8, t - 1, flags + 4, t - 4);
            const _Float16* rd = in0 + (t & 3) * SL0;
            half8 a0 = *(const half8*)(rd + arow);
            half8 a1 = *(const half8*)(rd + arow + 32);
            half8 a2 = *(const half8*)(rd + arow + 64);
            float4v acc[4];
#pragma unroll
            for (int g = 0; g < 4; ++g)
                acc[g] = __builtin_amdgcn_mfma_f32_16x16x32_f16(a0, wf[g][0], biasC[g], 0, 0, 0);
#pragma unroll
            for (int g = 0; g < 4; ++g)
                acc[g] = __builtin_amdgcn_mfma_f32_16x16x32_f16(a1, wf[g][1], acc[g], 0, 0, 0);
#pragma unroll
            for (int g = 0; g < 4; ++g)
                acc[g] = __builtin_amdgcn_mfma_f32_16x16x32_f16(a2, wf[g][2], acc[g], 0, 0, 0);
            float z[4];
#pragma unroll
            for (int g = 0; g < 4; ++g) z[g] = sel4(acc[g], q);
            float h = gate_update(z, c);
            _Float16 hf = (_Float16)h;
            in0[((t + 1) & 3) * SL0 + b * S0 + 32 + u] = hf;  // own recurrence
            in1[(t & 3) * SL1 + b * S1 + u]            = hf;  // L1 input
            __threadfence_block();
            if (l == 0) vfl[8 + w4] = t;
        }
    } else {                            // ===== L1 (role==1) / L2 (role==0) =====
        _Float16* rin  = role ? in1 : in2;
        _Float16* rout = role ? in2 : nullptr;
        const int* pa  = role ? (flags + 8) : (flags + 4);   // input producer
        const int* pb  = role ? (flags + 4) : (flags + 0);   // own layer
        for (int t = 0; t < TT; ++t) {
            if (role) poll3(pa, t, pb, t - 1, flags + 0, t - 4);
            else      poll2(pa, t, pb, t - 1);
            const _Float16* rd = rin + (t & 3) * SL1;
            half8 a0 = *(const half8*)(rd + arow);
            half8 a1 = *(const half8*)(rd + arow + 32);
            half8 a2 = *(const half8*)(rd + arow + 64);
            half8 a3 = *(const half8*)(rd + arow + 96);
            float4v acc[4];
#pragma unroll
            for (int g = 0; g < 4; ++g)
                acc[g] = __builtin_amdgcn_mfma_f32_16x16x32_f16(a0, wf[g][0], biasC[g], 0, 0, 0);
#pragma unroll
            for (int g = 0; g < 4; ++g)
                acc[g] = __builtin_amdgcn_mfma_f32_16x16x32_f16(a1, wf[g][1], acc[g], 0, 0, 0);
#pragma unroll
            for (int g = 0; g < 4; ++g)
                acc[g] = __builtin_amdgcn_mfma_f32_16x16x32_f16(a2, wf[g][2], acc[g], 0, 0, 0);
#pragma unroll
            for (int g = 0; g < 4; ++g)
                acc[g] = __builtin_amdgcn_mfma_f32_16x16x32_f16(a3, wf[g][3], acc[g], 0, 0, 0);
            float z[4];
#pragma unroll
            for (int g = 0; g < 4; ++g) z[g] = sel4(acc[g], q);
            float h = gate_update(z, c);
            _Float16 hf = (_Float16)h;
            rin[((t + 1) & 3) * SL1 + b * S1 + 64 + u] = hf;  // own recurrence
            if (role) rout[(t & 3) * SL1 + b * S1 + u] = hf;  // L2 input
            else if (t == TT - 1) fcA[b * 64 + u] = h;        // final h2 -> FC (fp32)
            __threadfence_block();
            if (l == 0) vfl[(role ? 4 : 0) + w4] = t;
        }
    }

    __syncthreads();   // single barrier before FC head

    // ================= FC head (fp32) =================
    for (int i = tid; i < 54 * 64; i += 1024) fcW[(i >> 6) * 65 + (i & 63)] = w0[i];
    for (int i = tid; i < 54; i += 1024) {
        fcP[i] = b0[i]; fcP[64 + i] = g0[i]; fcP[128 + i] = be0[i];
        fcP[192 + i] = m0[i]; fcP[256 + i] = v0[i];
    }
    __syncthreads();
    for (int idx = tid; idx < BB * 54; idx += 1024) {
        const int bb = idx / 54, j = idx - bb * 54;
        float s = fcP[j];
        for (int k = 0; k < 64; ++k) s += fcW[j * 65 + k] * fcA[bb * 64 + k];
        s = (s - fcP[192 + j]) * rsqrtf(fcP[256 + j] + 1e-5f) * fcP[64 + j] + fcP[128 + j];
        fcB[bb * 64 + j] = fmaxf(s, 0.0f);
    }
    __syncthreads();

    for (int i = tid; i < 44 * 54; i += 1024) fcW[(i / 54) * 55 + (i % 54)] = w1[i];
    for (int i = tid; i < 44; i += 1024) {
        fcP[i] = b1[i]; fcP[64 + i] = g1[i]; fcP[128 + i] = be1[i];
        fcP[192 + i] = m1[i]; fcP[256 + i] = v1[i];
    }
    __syncthreads();
    for (int idx = tid; idx < BB * 44; idx += 1024) {
        const int bb = idx / 44, j = idx - bb * 44;
        float s = fcP[j];
        for (int k = 0; k < 54; ++k) s += fcW[j * 55 + k] * fcB[bb * 64 + k];
        s = (s - fcP[192 + j]) * rsqrtf(fcP[256 + j] + 1e-5f) * fcP[64 + j] + fcP[128 + j];
        fcA[bb * 64 + j] = fmaxf(s, 0.0f);
    }
    __syncthreads();

    for (int i = tid; i < 24 * 44; i += 1024) fcW[(i / 44) * 45 + (i % 44)] = w2[i];
    for (int i = tid; i < 24; i += 1024) {
        fcP[i] = b2[i]; fcP[64 + i] = g2[i]; fcP[128 + i] = be2[i];
        fcP[192 + i] = m2[i]; fcP[256 + i] = v2[i];
    }
    __syncthreads();
    for (int idx = tid; idx < BB * 24; idx += 1024) {
        const int bb = idx / 24, j = idx - bb * 24;
        float s = fcP[j];
        for (int k = 0; k < 44; ++k) s += fcW[j * 45 + k] * fcA[bb * 64 + k];
        s = (s - fcP[192 + j]) * rsqrtf(fcP[256 + j] + 1e-5f) * fcP[64 + j] + fcP[128 + j];
        fcB[bb * 64 + j] = fmaxf(s, 0.0f);
    }
    __syncthreads();

    for (int i = tid; i < 4 * 24; i += 1024) fcW[(i / 24) * 25 + (i % 24)] = w3[i];
    for (int i = tid; i < 4; i += 1024) fcP[i] = b3[i];
    __syncthreads();
    for (int idx = tid; idx < BB * 4; idx += 1024) {
        const int bb = idx / 4, j = idx - bb * 4;
        float s = fcP[j];
        for (int k = 0; k < 24; ++k) s += fcW[j * 25 + k] * fcB[bb * 64 + k];
        out[(size_t)(n0 + bb) * 4 + j] = s;
    }
}

extern "C" void kernel_launch(void* const* d_in, const int* in_sizes, int n_in,
                              void* d_out, int out_size, void* d_ws, size_t ws_size,
                              hipStream_t stream) {
    const float* p[33];
    for (int i = 0; i < 33; ++i) p[i] = (const float*)d_in[i];
    lstm_fused<<<NBLK, 1024, 0, stream>>>(
        p[0],
        p[1], p[2], p[3], p[4],
        p[5], p[6], p[7], p[8],
        p[9], p[10], p[11], p[12],
        p[13], p[14], p[15], p[16], p[17], p[18], p[19], p[20],
        p[21], p[22], p[23], p[24],
        p[25], p[26], p[27], p[28],
        p[29], p[30], p[31], p[32],
        (float*)d_out);
}

// Round 9
// 940.876 us; speedup vs baseline: 1.2676x; 1.2676x over previous
//
#include <hip/hip_runtime.h>
#include <hip/hip_fp16.h>

// N=1024, F=22, T=1000, H=64, gates 4H=256
// R9: barrier-free dataflow, ring depth 8, unroll-8 (immediate slot offsets),
// batched backpressure (monotone flags: check cons>=t-5 every 4 ticks),
// 2-load tight polls, raw v_rcp in gates.
// 896 threads = 14 waves: 0-3 L2, 4-7 L1, 8-11 L0, 12-13 x stager.
// Flags: [0..3]=L2, [4..7]=L1, [8..11]=L0, [12..13]=ST, [14..15]=BIG pad.
//   L2(t): L2>=t-1, L1>=t
//   L1(t): L1>=t-1, L0>=t ; every 4: L2>=t-5
//   L0(t): L0>=t-1, ST>=t ; every 4: L1>=t-5
//   ST(t): every 4: L0>=t-5
#define TT 1000
#define FF 22
#define HH 64
#define BB 4
#define NBLK 256
#define S0 112
#define S1 144
#define SL0 (4 * S0)
#define SL1 (4 * S1)

typedef _Float16 half8 __attribute__((ext_vector_type(8)));
typedef float float4v __attribute__((ext_vector_type(4)));

__device__ __forceinline__ float sigm(float v) {
    return __builtin_amdgcn_rcpf(1.0f + __expf(-v));
}
__device__ __forceinline__ float tanh_(float v) {
    return 1.0f - 2.0f * __builtin_amdgcn_rcpf(__expf(2.0f * v) + 1.0f);
}

__device__ __forceinline__ float sel4(const float4v a, int q) {
    float lo = (q & 2) ? a[2] : a[0];
    float hi = (q & 2) ? a[3] : a[1];
    return (q & 1) ? hi : lo;
}

__device__ __forceinline__ float gate_update(const float z[4], float& c) {
    float cc = sigm(z[1]) * c + sigm(z[0]) * tanh_(z[2]);
    c = cc;
    return sigm(z[3]) * tanh_(cc);
}

__device__ __forceinline__ int ldmin4(const int* p) {
    int4 v = *(const int4*)p;
    return min(min(v.x, v.y), min(v.z, v.w));
}

extern "C" __global__ void __launch_bounds__(896, 1)
lstm_fused(const float* __restrict__ x,
           const float* __restrict__ Wih0, const float* __restrict__ Whh0,
           const float* __restrict__ bih0, const float* __restrict__ bhh0,
           const float* __restrict__ Wih1, const float* __restrict__ Whh1,
           const float* __restrict__ bih1, const float* __restrict__ bhh1,
           const float* __restrict__ Wih2, const float* __restrict__ Whh2,
           const float* __restrict__ bih2, const float* __restrict__ bhh2,
           const float* __restrict__ w0, const float* __restrict__ b0,
           const float* __restrict__ w1, const float* __restrict__ b1,
           const float* __restrict__ w2, const float* __restrict__ b2,
           const float* __restrict__ w3, const float* __restrict__ b3,
           const float* __restrict__ g0, const float* __restrict__ be0,
           const float* __restrict__ m0, const float* __restrict__ v0,
           const float* __restrict__ g1, const float* __restrict__ be1,
           const float* __restrict__ m1, const float* __restrict__ v1,
           const float* __restrict__ g2, const float* __restrict__ be2,
           const float* __restrict__ m2, const float* __restrict__ v2,
           float* __restrict__ out)
{
    __shared__ __align__(16) _Float16 in0[8 * SL0];
    __shared__ __align__(16) _Float16 in1[8 * SL1];
    __shared__ __align__(16) _Float16 in2[8 * SL1];
    __shared__ __align__(16) int flags[16];
    __shared__ float fcA[BB * 64];
    __shared__ float fcB[BB * 64];
    __shared__ float fcW[54 * 65];
    __shared__ float fcP[5 * 64];

    const int tid  = threadIdx.x;
    const int wv   = tid >> 6;      // 0..13
    const int role = wv >> 2;       // 0=L2, 1=L1, 2=L0, 3=stager
    const int w4   = wv & 3;
    const int l    = tid & 63;
    const int q    = l >> 4;
    const int l15  = l & 15;
    const int u    = 16 * w4 + l15;
    const int b    = q;
    const int n0   = blockIdx.x * BB;

    for (int i = tid; i < 8 * SL0; i += 896) in0[i] = (_Float16)0.0f;
    for (int i = tid; i < 8 * SL1; i += 896) in1[i] = (_Float16)0.0f;
    for (int i = tid; i < 8 * SL1; i += 896) in2[i] = (_Float16)0.0f;
    if (tid < 16) flags[tid] = (tid >= 14) ? (1 << 29) : -1;

    // ---- weight B-fragments: one unit per wave ----
    half8 wf[4][4];
    float4v biasC[4];
    if (role == 2) {                 // layer 0
#pragma unroll
        for (int g = 0; g < 4; ++g) {
            const int row = 64 * g + u;
#pragma unroll
            for (int kt = 0; kt < 3; ++kt) {
                half8 h{};
#pragma unroll
                for (int j = 0; j < 8; ++j) {
                    const int k = 32 * kt + 8 * q + j;
                    float val = 0.0f;
                    if (k < 32) { if (k < FF) val = Wih0[row * FF + k]; }
                    else        { val = Whh0[row * HH + (k - 32)]; }
                    h[j] = (_Float16)val;
                }
                wf[g][kt] = h;
            }
            float bv = bih0[row] + bhh0[row];
            biasC[g] = float4v{bv, bv, bv, bv};
        }
    } else if (role < 2) {           // 0 -> layer 2, 1 -> layer 1
        const float* Wih = role ? Wih1 : Wih2;
        const float* Whh = role ? Whh1 : Whh2;
        const float* bih = role ? bih1 : bih2;
        const float* bhh = role ? bhh1 : bhh2;
#pragma unroll
        for (int g = 0; g < 4; ++g) {
            const int row = 64 * g + u;
#pragma unroll
            for (int kt = 0; kt < 4; ++kt) {
                half8 h{};
#pragma unroll
                for (int j = 0; j < 8; ++j) {
                    const int k = 32 * kt + 8 * q + j;
                    h[j] = (_Float16)((k < 64) ? Wih[row * HH + k] : Whh[row * HH + (k - 64)]);
                }
                wf[g][kt] = h;
            }
            float bv = bih[row] + bhh[row];
            biasC[g] = float4v{bv, bv, bv, bv};
        }
    }

    // ---- x staging lanes: waves 12-13, 88 items ----
    const int  st  = tid - 768;
    const bool xok = (role == 3) && (st >= 0) && (st < BB * FF);
    const int  xb  = xok ? (st / FF) : 0;
    const int  xf  = xok ? (st - xb * FF) : 0;
    const float* xp = x + ((size_t)(n0 + xb) * FF + xf) * TT;

    volatile int* vfl = (volatile int*)flags;
    __syncthreads();

    const int arow = (role == 2) ? ((l15 & 3) * S0 + q * 8) : ((l15 & 3) * S1 + q * 8);
    float c = 0.f;

#define SPIN(cond) do { for (;;) { asm volatile("" ::: "memory"); if (cond) break; \
                        __builtin_amdgcn_s_sleep(1); } __threadfence_block(); } while (0)

    if (role == 3) {                   // ===== stager =====
        float xh = xok ? xp[0] : 0.f;
        for (int k = 0; k < 125; ++k) {
            const int tb = k * 8;
#pragma unroll
            for (int s = 0; s < 8; ++s) {
                const int t = tb + s;
                if ((s & 3) == 0) SPIN(ldmin4(flags + 8) >= t - 5);
                if (xok) in0[s * SL0 + xb * S0 + xf] = (_Float16)xh;
                __threadfence_block();
                if (l == 0) vfl[12 + (wv - 12)] = t;
                if (xok) xh = xp[(t + 1 < TT) ? (t + 1) : (TT - 1)];
            }
        }
    } else if (role == 2) {            // ===== L0 =====
        for (int k = 0; k < 125; ++k) {
            const int tb = k * 8;
#pragma unroll
            for (int s = 0; s < 8; ++s) {
                const int t = tb + s;
                if ((s & 3) == 0)
                    SPIN(ldmin4(flags + 8) >= t - 1 && ldmin4(flags + 12) >= t &&
                         ldmin4(flags + 4) >= t - 5);
                else
                    SPIN(ldmin4(flags + 8) >= t - 1 && ldmin4(flags + 12) >= t);
                const _Float16* rd = in0 + s * SL0;
                half8 a0 = *(const half8*)(rd + arow);
                half8 a1 = *(const half8*)(rd + arow + 32);
                half8 a2 = *(const half8*)(rd + arow + 64);
                float4v acc[4];
#pragma unroll
                for (int g = 0; g < 4; ++g)
                    acc[g] = __builtin_amdgcn_mfma_f32_16x16x32_f16(a0, wf[g][0], biasC[g], 0, 0, 0);
#pragma unroll
                for (int g = 0; g < 4; ++g)
                    acc[g] = __builtin_amdgcn_mfma_f32_16x16x32_f16(a1, wf[g][1], acc[g], 0, 0, 0);
#pragma unroll
                for (int g = 0; g < 4; ++g)
                    acc[g] = __builtin_amdgcn_mfma_f32_16x16x32_f16(a2, wf[g][2], acc[g], 0, 0, 0);
                float z[4];
#pragma unroll
                for (int g = 0; g < 4; ++g) z[g] = sel4(acc[g], q);
                float h = gate_update(z, c);
                _Float16 hf = (_Float16)h;
                in0[((s + 1) & 7) * SL0 + b * S0 + 32 + u] = hf; // own rec
                in1[s * SL1 + b * S1 + u]                  = hf; // L1 input
                __threadfence_block();
                if (l == 0) vfl[8 + w4] = t;
            }
        }
    } else {                            // ===== L1 (role==1) / L2 (role==0) =====
        _Float16* rin  = role ? in1 : in2;
        _Float16* rout = role ? in2 : nullptr;
        const int* pin = role ? (flags + 8) : (flags + 4);  // input producer group
        const int* pow_ = role ? (flags + 4) : (flags + 0); // own group
        for (int k = 0; k < 125; ++k) {
            const int tb = k * 8;
#pragma unroll
            for (int s = 0; s < 8; ++s) {
                const int t = tb + s;
                if (role && (s & 3) == 0)
                    SPIN(ldmin4(pow_) >= t - 1 && ldmin4(pin) >= t &&
                         ldmin4(flags + 0) >= t - 5);
                else
                    SPIN(ldmin4(pow_) >= t - 1 && ldmin4(pin) >= t);
                const _Float16* rd = rin + s * SL1;
                half8 a0 = *(const half8*)(rd + arow);
                half8 a1 = *(const half8*)(rd + arow + 32);
                half8 a2 = *(const half8*)(rd + arow + 64);
                half8 a3 = *(const half8*)(rd + arow + 96);
                float4v acc[4];
#pragma unroll
                for (int g = 0; g < 4; ++g)
                    acc[g] = __builtin_amdgcn_mfma_f32_16x16x32_f16(a0, wf[g][0], biasC[g], 0, 0, 0);
#pragma unroll
                for (int g = 0; g < 4; ++g)
                    acc[g] = __builtin_amdgcn_mfma_f32_16x16x32_f16(a1, wf[g][1], acc[g], 0, 0, 0);
#pragma unroll
                for (int g = 0; g < 4; ++g)
                    acc[g] = __builtin_amdgcn_mfma_f32_16x16x32_f16(a2, wf[g][2], acc[g], 0, 0, 0);
#pragma unroll
                for (int g = 0; g < 4; ++g)
                    acc[g] = __builtin_amdgcn_mfma_f32_16x16x32_f16(a3, wf[g][3], acc[g], 0, 0, 0);
                float z[4];
#pragma unroll
                for (int g = 0; g < 4; ++g) z[g] = sel4(acc[g], q);
                float h = gate_update(z, c);
                _Float16 hf = (_Float16)h;
                if (role) {
                    rin[((s + 1) & 7) * SL1 + b * S1 + 64 + u] = hf; // own rec
                    rout[s * SL1 + b * S1 + u]                 = hf; // L2 input
                } else {
                    if (t != TT - 1) rin[((s + 1) & 7) * SL1 + b * S1 + 64 + u] = hf;
                    else             fcA[b * 64 + u] = h;            // final h2 (fp32)
                }
                __threadfence_block();
                if (l == 0) vfl[(role ? 4 : 0) + w4] = t;
            }
        }
    }
#undef SPIN

    __syncthreads();

    // ================= FC head (fp32) =================
    for (int i = tid; i < 54 * 64; i += 896) fcW[(i >> 6) * 65 + (i & 63)] = w0[i];
    for (int i = tid; i < 54; i += 896) {
        fcP[i] = b0[i]; fcP[64 + i] = g0[i]; fcP[128 + i] = be0[i];
        fcP[192 + i] = m0[i]; fcP[256 + i] = v0[i];
    }
    __syncthreads();
    for (int idx = tid; idx < BB * 54; idx += 896) {
        const int bb = idx / 54, j = idx - bb * 54;
        float s = fcP[j];
        for (int k = 0; k < 64; ++k) s += fcW[j * 65 + k] * fcA[bb * 64 + k];
        s = (s - fcP[192 + j]) * rsqrtf(fcP[256 + j] + 1e-5f) * fcP[64 + j] + fcP[128 + j];
        fcB[bb * 64 + j] = fmaxf(s, 0.0f);
    }
    __syncthreads();

    for (int i = tid; i < 44 * 54; i += 896) fcW[(i / 54) * 55 + (i % 54)] = w1[i];
    for (int i = tid; i < 44; i += 896) {
        fcP[i] = b1[i]; fcP[64 + i] = g1[i]; fcP[128 + i] = be1[i];
        fcP[192 + i] = m1[i]; fcP[256 + i] = v1[i];
    }
    __syncthreads();
    for (int idx = tid; idx < BB * 44; idx += 896) {
        const int bb = idx / 44, j = idx - bb * 44;
        float s = fcP[j];
        for (int k = 0; k < 54; ++k) s += fcW[j * 55 + k] * fcB[bb * 64 + k];
        s = (s - fcP[192 + j]) * rsqrtf(fcP[256 + j] + 1e-5f) * fcP[64 + j] + fcP[128 + j];
        fcA[bb * 64 + j] = fmaxf(s, 0.0f);
    }
    __syncthreads();

    for (int i = tid; i < 24 * 44; i += 896) fcW[(i / 44) * 45 + (i % 44)] = w2[i];
    for (int i = tid; i < 24; i += 896) {
        fcP[i] = b2[i]; fcP[64 + i] = g2[i]; fcP[128 + i] = be2[i];
        fcP[192 + i] = m2[i]; fcP[256 + i] = v2[i];
    }
    __syncthreads();
    for (int idx = tid; idx < BB * 24; idx += 896) {
        const int bb = idx / 24, j = idx - bb * 24;
        float s = fcP[j];
        for (int k = 0; k < 44; ++k) s += fcW[j * 45 + k] * fcA[bb * 64 + k];
        s = (s - fcP[192 + j]) * rsqrtf(fcP[256 + j] + 1e-5f) * fcP[64 + j] + fcP[128 + j];
        fcB[bb * 64 + j] = fmaxf(s, 0.0f);
    }
    __syncthreads();

    for (int i = tid; i < 4 * 24; i += 896) fcW[(i / 24) * 25 + (i % 24)] = w3[i];
    for (int i = tid; i < 4; i += 896) fcP[i] = b3[i];
    __syncthreads();
    for (int idx = tid; idx < BB * 4; idx += 896) {
        const int bb = idx / 4, j = idx - bb * 4;
        float s = fcP[j];
        for (int k = 0; k < 24; ++k) s += fcW[j * 25 + k] * fcB[bb * 64 + k];
        out[(size_t)(n0 + bb) * 4 + j] = s;
    }
}

extern "C" void kernel_launch(void* const* d_in, const int* in_sizes, int n_in,
                              void* d_out, int out_size, void* d_ws, size_t ws_size,
                              hipStream_t stream) {
    const float* p[33];
    for (int i = 0; i < 33; ++i) p[i] = (const float*)d_in[i];
    lstm_fused<<<NBLK, 896, 0, stream>>>(
        p[0],
        p[1], p[2], p[3], p[4],
        p[5], p[6], p[7], p[8],
        p[9], p[10], p[11], p[12],
        p[13], p[14], p[15], p[16], p[17], p[18], p[19], p[20],
        p[21], p[22], p[23], p[24],
        p[25], p[26], p[27], p[28],
        p[29], p[30], p[31], p[32],
        (float*)d_out);
}

// Round 10
// 817.106 us; speedup vs baseline: 1.4596x; 1.1515x over previous
//
#include <hip/hip_runtime.h>
#include <hip/hip_fp16.h>

// N=1024, F=22, T=1000, H=64, gates 4H=256
// R10: barrier-free dataflow + AMORTIZED LEAD-3 POLLS.
// 896 threads = 14 waves: 0-3 L2, 4-7 L1, 8-11 L0, 12-13 x stager.
// Ring depth 8, unroll-8 (immediate slot offsets). Flags monotone tick counters:
//   [0..3]=L2, [4..7]=L1, [8..11]=L0, [12..13]=ST, [14..15]=BIG pad.
// Every tick (compute waves): own-group >= t-1   (tight; siblings can't lead)
// Every 4 ticks at t0:
//   L2: L1 >= t0+3
//   L1: L0 >= t0+3  && L2 >= t0-5
//   L0: ST >= t0+3  && L1 >= t0-5
//   ST: L0 >= t0-5
// Monotonicity makes ticks t0..t0+3 poll-free on cross-layer edges.
// Leads bounded in [3,8]; ring-8 overwrite distances safe (audited).
#define TT 1000
#define FF 22
#define HH 64
#define BB 4
#define NBLK 256
#define S0 112
#define S1 144
#define SL0 (4 * S0)
#define SL1 (4 * S1)

typedef _Float16 half8 __attribute__((ext_vector_type(8)));
typedef float float4v __attribute__((ext_vector_type(4)));

__device__ __forceinline__ float sigm(float v) {
    return __builtin_amdgcn_rcpf(1.0f + __expf(-v));
}
__device__ __forceinline__ float tanh_(float v) {
    return 1.0f - 2.0f * __builtin_amdgcn_rcpf(__expf(2.0f * v) + 1.0f);
}

__device__ __forceinline__ float sel4(const float4v a, int q) {
    float lo = (q & 2) ? a[2] : a[0];
    float hi = (q & 2) ? a[3] : a[1];
    return (q & 1) ? hi : lo;
}

__device__ __forceinline__ float gate_update(const float z[4], float& c) {
    float cc = sigm(z[1]) * c + sigm(z[0]) * tanh_(z[2]);
    c = cc;
    return sigm(z[3]) * tanh_(cc);
}

__device__ __forceinline__ int ldmin4(const int* p) {
    int4 v = *(const int4*)p;
    return min(min(v.x, v.y), min(v.z, v.w));
}

// spin until cond; compiler clobber only (no lgkm drain on success path)
#define SPIN(cond) do { for (;;) { asm volatile("" ::: "memory"); if (cond) break; \
                        __builtin_amdgcn_s_sleep(1); } asm volatile("" ::: "memory"); } while (0)

extern "C" __global__ void __launch_bounds__(896, 1)
lstm_fused(const float* __restrict__ x,
           const float* __restrict__ Wih0, const float* __restrict__ Whh0,
           const float* __restrict__ bih0, const float* __restrict__ bhh0,
           const float* __restrict__ Wih1, const float* __restrict__ Whh1,
           const float* __restrict__ bih1, const float* __restrict__ bhh1,
           const float* __restrict__ Wih2, const float* __restrict__ Whh2,
           const float* __restrict__ bih2, const float* __restrict__ bhh2,
           const float* __restrict__ w0, const float* __restrict__ b0,
           const float* __restrict__ w1, const float* __restrict__ b1,
           const float* __restrict__ w2, const float* __restrict__ b2,
           const float* __restrict__ w3, const float* __restrict__ b3,
           const float* __restrict__ g0, const float* __restrict__ be0,
           const float* __restrict__ m0, const float* __restrict__ v0,
           const float* __restrict__ g1, const float* __restrict__ be1,
           const float* __restrict__ m1, const float* __restrict__ v1,
           const float* __restrict__ g2, const float* __restrict__ be2,
           const float* __restrict__ m2, const float* __restrict__ v2,
           float* __restrict__ out)
{
    __shared__ __align__(16) _Float16 in0[8 * SL0];
    __shared__ __align__(16) _Float16 in1[8 * SL1];
    __shared__ __align__(16) _Float16 in2[8 * SL1];
    __shared__ __align__(16) int flags[16];
    __shared__ float fcA[BB * 64];
    __shared__ float fcB[BB * 64];
    __shared__ float fcW[54 * 65];
    __shared__ float fcP[5 * 64];

    const int tid  = threadIdx.x;
    const int wv   = tid >> 6;      // 0..13
    const int role = wv >> 2;       // 0=L2, 1=L1, 2=L0, 3=stager
    const int w4   = wv & 3;
    const int l    = tid & 63;
    const int q    = l >> 4;
    const int l15  = l & 15;
    const int u    = 16 * w4 + l15;
    const int b    = q;
    const int n0   = blockIdx.x * BB;

    for (int i = tid; i < 8 * SL0; i += 896) in0[i] = (_Float16)0.0f;
    for (int i = tid; i < 8 * SL1; i += 896) in1[i] = (_Float16)0.0f;
    for (int i = tid; i < 8 * SL1; i += 896) in2[i] = (_Float16)0.0f;
    if (tid < 16) flags[tid] = (tid >= 14) ? (1 << 29) : -1;

    // ---- weight B-fragments: one unit per wave ----
    half8 wf[4][4];
    float4v biasC[4];
    if (role == 2) {                 // layer 0
#pragma unroll
        for (int g = 0; g < 4; ++g) {
            const int row = 64 * g + u;
#pragma unroll
            for (int kt = 0; kt < 3; ++kt) {
                half8 h{};
#pragma unroll
                for (int j = 0; j < 8; ++j) {
                    const int k = 32 * kt + 8 * q + j;
                    float val = 0.0f;
                    if (k < 32) { if (k < FF) val = Wih0[row * FF + k]; }
                    else        { val = Whh0[row * HH + (k - 32)]; }
                    h[j] = (_Float16)val;
                }
                wf[g][kt] = h;
            }
            float bv = bih0[row] + bhh0[row];
            biasC[g] = float4v{bv, bv, bv, bv};
        }
    } else if (role < 2) {           // 0 -> layer 2, 1 -> layer 1
        const float* Wih = role ? Wih1 : Wih2;
        const float* Whh = role ? Whh1 : Whh2;
        const float* bih = role ? bih1 : bih2;
        const float* bhh = role ? bhh1 : bhh2;
#pragma unroll
        for (int g = 0; g < 4; ++g) {
            const int row = 64 * g + u;
#pragma unroll
            for (int kt = 0; kt < 4; ++kt) {
                half8 h{};
#pragma unroll
                for (int j = 0; j < 8; ++j) {
                    const int k = 32 * kt + 8 * q + j;
                    h[j] = (_Float16)((k < 64) ? Wih[row * HH + k] : Whh[row * HH + (k - 64)]);
                }
                wf[g][kt] = h;
            }
            float bv = bih[row] + bhh[row];
            biasC[g] = float4v{bv, bv, bv, bv};
        }
    }

    // ---- x staging lanes: waves 12-13, 88 items ----
    const int  st  = tid - 768;
    const bool xok = (role == 3) && (st >= 0) && (st < BB * FF);
    const int  xb  = xok ? (st / FF) : 0;
    const int  xf  = xok ? (st - xb * FF) : 0;
    const float* xp = x + ((size_t)(n0 + xb) * FF + xf) * TT;

    volatile int* vfl = (volatile int*)flags;
    __syncthreads();

    const int arow = (role == 2) ? ((l15 & 3) * S0 + q * 8) : ((l15 & 3) * S1 + q * 8);
    float c = 0.f;

    if (role == 3) {                   // ===== stager =====
        float xh = xok ? xp[0] : 0.f;
        for (int k = 0; k < 125; ++k) {
            const int tb = k * 8;
#pragma unroll
            for (int s = 0; s < 8; ++s) {
                const int t = tb + s;
                if ((s & 3) == 0) SPIN(ldmin4(flags + 8) >= t - 5);
                if (xok) in0[s * SL0 + xb * S0 + xf] = (_Float16)xh;
                __threadfence_block();
                if (l == 0) vfl[12 + (wv - 12)] = t;
                if (xok) xh = xp[(t + 1 < TT) ? (t + 1) : (TT - 1)];
            }
        }
    } else if (role == 2) {            // ===== L0 =====
        for (int k = 0; k < 125; ++k) {
            const int tb = k * 8;
#pragma unroll
            for (int s = 0; s < 8; ++s) {
                const int t = tb + s;
                if ((s & 3) == 0)
                    SPIN(ldmin4(flags + 12) >= t + 3 && ldmin4(flags + 4) >= t - 5);
                SPIN(ldmin4(flags + 8) >= t - 1);   // siblings, tight
                const _Float16* rd = in0 + s * SL0;
                half8 a0 = *(const half8*)(rd + arow);
                half8 a1 = *(const half8*)(rd + arow + 32);
                half8 a2 = *(const half8*)(rd + arow + 64);
                float4v acc[4];
#pragma unroll
                for (int g = 0; g < 4; ++g)
                    acc[g] = __builtin_amdgcn_mfma_f32_16x16x32_f16(a0, wf[g][0], biasC[g], 0, 0, 0);
#pragma unroll
                for (int g = 0; g < 4; ++g)
                    acc[g] = __builtin_amdgcn_mfma_f32_16x16x32_f16(a1, wf[g][1], acc[g], 0, 0, 0);
#pragma unroll
                for (int g = 0; g < 4; ++g)
                    acc[g] = __builtin_amdgcn_mfma_f32_16x16x32_f16(a2, wf[g][2], acc[g], 0, 0, 0);
                float z[4];
#pragma unroll
                for (int g = 0; g < 4; ++g) z[g] = sel4(acc[g], q);
                float h = gate_update(z, c);
                _Float16 hf = (_Float16)h;
                in0[((s + 1) & 7) * SL0 + b * S0 + 32 + u] = hf; // own rec
                in1[s * SL1 + b * S1 + u]                  = hf; // L1 input
                __threadfence_block();
                if (l == 0) vfl[8 + w4] = t;
            }
        }
    } else {                            // ===== L1 (role==1) / L2 (role==0) =====
        _Float16* rin  = role ? in1 : in2;
        _Float16* rout = role ? in2 : nullptr;
        const int* pin = role ? (flags + 8) : (flags + 4);  // input producer group
        const int* pow_ = role ? (flags + 4) : (flags + 0); // own group
        for (int k = 0; k < 125; ++k) {
            const int tb = k * 8;
#pragma unroll
            for (int s = 0; s < 8; ++s) {
                const int t = tb + s;
                if ((s & 3) == 0) {
                    if (role) SPIN(ldmin4(pin) >= t + 3 && ldmin4(flags + 0) >= t - 5);
                    else      SPIN(ldmin4(pin) >= t + 3);
                }
                SPIN(ldmin4(pow_) >= t - 1);        // siblings, tight
                const _Float16* rd = rin + s * SL1;
                half8 a0 = *(const half8*)(rd + arow);
                half8 a1 = *(const half8*)(rd + arow + 32);
                half8 a2 = *(const half8*)(rd + arow + 64);
                half8 a3 = *(const half8*)(rd + arow + 96);
                float4v acc[4];
#pragma unroll
                for (int g = 0; g < 4; ++g)
                    acc[g] = __builtin_amdgcn_mfma_f32_16x16x32_f16(a0, wf[g][0], biasC[g], 0, 0, 0);
#pragma unroll
                for (int g = 0; g < 4; ++g)
                    acc[g] = __builtin_amdgcn_mfma_f32_16x16x32_f16(a1, wf[g][1], acc[g], 0, 0, 0);
#pragma unroll
                for (int g = 0; g < 4; ++g)
                    acc[g] = __builtin_amdgcn_mfma_f32_16x16x32_f16(a2, wf[g][2], acc[g], 0, 0, 0);
#pragma unroll
                for (int g = 0; g < 4; ++g)
                    acc[g] = __builtin_amdgcn_mfma_f32_16x16x32_f16(a3, wf[g][3], acc[g], 0, 0, 0);
                float z[4];
#pragma unroll
                for (int g = 0; g < 4; ++g) z[g] = sel4(acc[g], q);
                float h = gate_update(z, c);
                _Float16 hf = (_Float16)h;
                if (role) {
                    rin[((s + 1) & 7) * SL1 + b * S1 + 64 + u] = hf; // own rec
                    rout[s * SL1 + b * S1 + u]                 = hf; // L2 input
                } else {
                    if (t != TT - 1) rin[((s + 1) & 7) * SL1 + b * S1 + 64 + u] = hf;
                    else             fcA[b * 64 + u] = h;            // final h2 (fp32)
                }
                __threadfence_block();
                if (l == 0) vfl[(role ? 4 : 0) + w4] = t;
            }
        }
    }

    __syncthreads();

    // ================= FC head (fp32) =================
    for (int i = tid; i < 54 * 64; i += 896) fcW[(i >> 6) * 65 + (i & 63)] = w0[i];
    for (int i = tid; i < 54; i += 896) {
        fcP[i] = b0[i]; fcP[64 + i] = g0[i]; fcP[128 + i] = be0[i];
        fcP[192 + i] = m0[i]; fcP[256 + i] = v0[i];
    }
    __syncthreads();
    for (int idx = tid; idx < BB * 54; idx += 896) {
        const int bb = idx / 54, j = idx - bb * 54;
        float s = fcP[j];
        for (int k = 0; k < 64; ++k) s += fcW[j * 65 + k] * fcA[bb * 64 + k];
        s = (s - fcP[192 + j]) * rsqrtf(fcP[256 + j] + 1e-5f) * fcP[64 + j] + fcP[128 + j];
        fcB[bb * 64 + j] = fmaxf(s, 0.0f);
    }
    __syncthreads();

    for (int i = tid; i < 44 * 54; i += 896) fcW[(i / 54) * 55 + (i % 54)] = w1[i];
    for (int i = tid; i < 44; i += 896) {
        fcP[i] = b1[i]; fcP[64 + i] = g1[i]; fcP[128 + i] = be1[i];
        fcP[192 + i] = m1[i]; fcP[256 + i] = v1[i];
    }
    __syncthreads();
    for (int idx = tid; idx < BB * 44; idx += 896) {
        const int bb = idx / 44, j = idx - bb * 44;
        float s = fcP[j];
        for (int k = 0; k < 54; ++k) s += fcW[j * 55 + k] * fcB[bb * 64 + k];
        s = (s - fcP[192 + j]) * rsqrtf(fcP[256 + j] + 1e-5f) * fcP[64 + j] + fcP[128 + j];
        fcA[bb * 64 + j] = fmaxf(s, 0.0f);
    }
    __syncthreads();

    for (int i = tid; i < 24 * 44; i += 896) fcW[(i / 44) * 45 + (i % 44)] = w2[i];
    for (int i = tid; i < 24; i += 896) {
        fcP[i] = b2[i]; fcP[64 + i] = g2[i]; fcP[128 + i] = be2[i];
        fcP[192 + i] = m2[i]; fcP[256 + i] = v2[i];
    }
    __syncthreads();
    for (int idx = tid; idx < BB * 24; idx += 896) {
        const int bb = idx / 24, j = idx - bb * 24;
        float s = fcP[j];
        for (int k = 0; k < 44; ++k) s += fcW[j * 45 + k] * fcA[bb * 64 + k];
        s = (s - fcP[192 + j]) * rsqrtf(fcP[256 + j] + 1e-5f) * fcP[64 + j] + fcP[128 + j];
        fcB[bb * 64 + j] = fmaxf(s, 0.0f);
    }
    __syncthreads();

    for (int i = tid; i < 4 * 24; i += 896) fcW[(i / 24) * 25 + (i % 24)] = w3[i];
    for (int i = tid; i < 4; i += 896) fcP[i] = b3[i];
    __syncthreads();
    for (int idx = tid; idx < BB * 4; idx += 896) {
        const int bb = idx / 4, j = idx - bb * 4;
        float s = fcP[j];
        for (int k = 0; k < 24; ++k) s += fcW[j * 25 + k] * fcB[bb * 64 + k];
        out[(size_t)(n0 + bb) * 4 + j] = s;
    }
}

extern "C" void kernel_launch(void* const* d_in, const int* in_sizes, int n_in,
                              void* d_out, int out_size, void* d_ws, size_t ws_size,
                              hipStream_t stream) {
    const float* p[33];
    for (int i = 0; i < 33; ++i) p[i] = (const float*)d_in[i];
    lstm_fused<<<NBLK, 896, 0, stream>>>(
        p[0],
        p[1], p[2], p[3], p[4],
        p[5], p[6], p[7], p[8],
        p[9], p[10], p[11], p[12],
        p[13], p[14], p[15], p[16], p[17], p[18], p[19], p[20],
        p[21], p[22], p[23], p[24],
        p[25], p[26], p[27], p[28],
        p[29], p[30], p[31], p[32],
        (float*)d_out);
}